// Round 1
// baseline (5212.023 us; speedup 1.0000x reference)
//
#include <hip/hip_runtime.h>
#include <cmath>

#define DI __device__ __forceinline__

typedef unsigned short u16;
typedef __bf16 bf16x8 __attribute__((ext_vector_type(8)));
typedef float f32x4 __attribute__((ext_vector_type(4)));

static constexpr int Bsz = 2, T = 1024, D = 768, H = 12, FF = 3072, V = 50257, L = 12;
static constexpr int M = Bsz * T;  // 2048 rows

DI u16 f2bf(float f) {
  unsigned u = __float_as_uint(f);
  u = (u + 0x7fffu + ((u >> 16) & 1u)) >> 16;
  return (u16)u;
}
DI float bf2f(u16 h) { return __uint_as_float(((unsigned)h) << 16); }

DI void gload_lds16(const void* g, void* l) {
  __builtin_amdgcn_global_load_lds((const __attribute__((address_space(1))) void*)g,
                                   (__attribute__((address_space(3))) void*)l, 16, 0, 0);
}

// ---------------- transpose + convert: src f32 [R][C] -> dst bf16 [C][R] ----------------
__launch_bounds__(256)
__global__ void transpose_cvt(const float* __restrict__ src, u16* __restrict__ dst, int R, int C) {
  __shared__ float tile[32][33];
  const int tx = threadIdx.x, ty = threadIdx.y;
  const int c0 = blockIdx.x * 32, r0 = blockIdx.y * 32;
  src += (size_t)blockIdx.z * R * C;
  dst += (size_t)blockIdx.z * R * C;
#pragma unroll
  for (int i = 0; i < 4; ++i)
    tile[ty + i * 8][tx] = src[(size_t)(r0 + ty + i * 8) * C + c0 + tx];
  __syncthreads();
#pragma unroll
  for (int i = 0; i < 4; ++i)
    dst[(size_t)(c0 + ty + i * 8) * R + r0 + tx] = f2bf(tile[tx][ty + i * 8]);
}

// ---------------- plain convert f32 -> bf16 (tok_emb) ----------------
__global__ void convert_bf16(const float* __restrict__ src, u16* __restrict__ dst, long n4) {
  long i = (long)blockIdx.x * blockDim.x + threadIdx.x;
  long stride = (long)gridDim.x * blockDim.x;
  for (; i < n4; i += stride) {
    float4 f = ((const float4*)src)[i];
    ushort4 o;
    o.x = f2bf(f.x); o.y = f2bf(f.y); o.z = f2bf(f.z); o.w = f2bf(f.w);
    ((ushort4*)dst)[i] = o;
  }
}

// ---------------- embedding: h = tok_emb[x] + pos_emb ----------------
__launch_bounds__(256)
__global__ void embed_kernel(const int* __restrict__ x, const float* __restrict__ tok,
                             const float* __restrict__ pos, float* __restrict__ h) {
  const int row = blockIdx.x, t = threadIdx.x;
  const int tt = row % T;
  const int id = x[row];
  float* o = h + (size_t)row * D;
  const float* te = tok + (size_t)id * D;
  const float* pe = pos + (size_t)tt * D;
  o[t] = te[t] + pe[t];
  o[t + 256] = te[t + 256] + pe[t + 256];
  o[t + 512] = te[t + 512] + pe[t + 512];
}

// ---------------- LayerNorm (biased var), f32 in -> bf16 out ----------------
__launch_bounds__(256)
__global__ void layernorm_kernel(const float* __restrict__ in, const float* __restrict__ gw,
                                 const float* __restrict__ bw, u16* __restrict__ out) {
  const int row = blockIdx.x, t = threadIdx.x;
  const int lane = t & 63, wid = t >> 6;
  const float* x = in + (size_t)row * D;
  float v0 = x[t], v1 = x[t + 256], v2 = x[t + 512];
  float sum = v0 + v1 + v2;
  float sq = v0 * v0 + v1 * v1 + v2 * v2;
  for (int off = 1; off < 64; off <<= 1) {
    sum += __shfl_xor(sum, off);
    sq += __shfl_xor(sq, off);
  }
  __shared__ float ps[4], pq[4];
  if (lane == 0) { ps[wid] = sum; pq[wid] = sq; }
  __syncthreads();
  sum = ps[0] + ps[1] + ps[2] + ps[3];
  sq = pq[0] + pq[1] + pq[2] + pq[3];
  const float mean = sum * (1.0f / D);
  const float var = sq * (1.0f / D) - mean * mean;
  const float rstd = rsqrtf(var + 1e-5f);
  u16* o = out + (size_t)row * D;
  o[t] = f2bf((v0 - mean) * rstd * gw[t] + bw[t]);
  o[t + 256] = f2bf((v1 - mean) * rstd * gw[t + 256] + bw[t + 256]);
  o[t + 512] = f2bf((v2 - mean) * rstd * gw[t + 512] + bw[t + 512]);
}

// ---------------- NT bf16 GEMM: C[M][N] = A[M][K] * Bt[N][K]^T (+bias) ----------------
// m97 structure: 128x128 tile, 4 waves (2x2 of 64x64), BK=32, 16x16x32 MFMA.
// LDS chunk-swizzle: chunk' = chunk ^ (row & 3)  (16B chunks) on both stage-src and read.
// EPI: 0 = store bf16 (+bias); 1 = exact GELU then bf16 (+bias);
//      2 = f32 residual add (out = resid + acc + bias); 3 = store f32 (no bias use).
template <int EPI>
__launch_bounds__(256)
__global__ void gemm_nt(const u16* __restrict__ A, const u16* __restrict__ Bt,
                        const float* b0, const float* b1, const float* b2,
                        float* outF, u16* outH, const float* resid,
                        int N, int K, long zsB, long zsOut) {
  __shared__ u16 sA[128 * 32];
  __shared__ u16 sB[128 * 32];
  const int t = threadIdx.x;
  const int lane = t & 63, wid = t >> 6;
  const int m0 = blockIdx.x * 128, n0 = blockIdx.y * 128;
  const int z = blockIdx.z;
  Bt += (long)z * zsB;
  const float* bias = (z == 0) ? b0 : (z == 1 ? b1 : b2);
  if (outH) outH += (long)z * zsOut;

  f32x4 acc[4][4] = {};
  const int wr = (wid >> 1) * 64, wc = (wid & 1) * 64;
  const int rsel = lane & 15, ksel = lane >> 4;

  for (int k0 = 0; k0 < K; k0 += 32) {
#pragma unroll
    for (int i = 0; i < 2; ++i) {
      int c = t + i * 256;
      int row = c >> 2, ch = c & 3;
      int g = ch ^ (row & 3);
      gload_lds16(A + (size_t)(m0 + row) * K + k0 + g * 8, &sA[c * 8]);
    }
#pragma unroll
    for (int i = 0; i < 2; ++i) {
      int c = t + i * 256;
      int row = c >> 2, ch = c & 3;
      int g = ch ^ (row & 3);
      int nr = n0 + row;
      if (nr >= N) nr = N - 1;  // LM-head tail: duplicate row, stores are guarded
      gload_lds16(Bt + (size_t)nr * K + k0 + g * 8, &sB[c * 8]);
    }
    __syncthreads();
    bf16x8 af[4], bfr[4];
#pragma unroll
    for (int m = 0; m < 4; ++m) {
      int row = wr + m * 16 + rsel;
      int ch = ksel ^ (row & 3);
      af[m] = *(const bf16x8*)&sA[row * 32 + ch * 8];
    }
#pragma unroll
    for (int n = 0; n < 4; ++n) {
      int row = wc + n * 16 + rsel;
      int ch = ksel ^ (row & 3);
      bfr[n] = *(const bf16x8*)&sB[row * 32 + ch * 8];
    }
#pragma unroll
    for (int m = 0; m < 4; ++m)
#pragma unroll
      for (int n = 0; n < 4; ++n)
        acc[m][n] = __builtin_amdgcn_mfma_f32_16x16x32_bf16(af[m], bfr[n], acc[m][n], 0, 0, 0);
    __syncthreads();
  }

  const int rq = lane >> 4;
#pragma unroll
  for (int m = 0; m < 4; ++m) {
#pragma unroll
    for (int n = 0; n < 4; ++n) {
      const int col = n0 + wc + n * 16 + rsel;
      if (col >= N) continue;
      const float bv = bias ? bias[col] : 0.0f;
#pragma unroll
      for (int i = 0; i < 4; ++i) {
        const int row = m0 + wr + m * 16 + rq * 4 + i;
        float v = acc[m][n][i] + bv;
        const size_t idx = (size_t)row * N + col;
        if (EPI == 0) {
          outH[idx] = f2bf(v);
        } else if (EPI == 1) {
          float ge = 0.5f * v * (1.0f + erff(v * 0.70710678118f));
          outH[idx] = f2bf(ge);
        } else if (EPI == 2) {
          outF[idx] = resid[idx] + v;
        } else {
          outF[idx] = v;
        }
      }
    }
  }
}

// ---------------- causal flash attention (vector f32), 16 queries/block ----------------
__launch_bounds__(256)
__global__ void attn_kernel(const u16* __restrict__ qbuf, const u16* __restrict__ kbuf,
                            const u16* __restrict__ vbuf, u16* __restrict__ ctx) {
  __shared__ float sq[16 * 64];
  __shared__ float sk[64 * 64];
  __shared__ float sv[64 * 64];
  const int t = threadIdx.x, lane = t & 63, wid = t >> 6;
  const int q0 = blockIdx.x * 16;
  const int bh = blockIdx.y;
  const int b = bh / H, hh = bh % H;
  const size_t rowbase = (size_t)b * T;

  {  // stage q tile: 16 rows x 64 dims, no swizzle (reads are broadcast)
    int r = t >> 4, c4 = t & 15;
    ushort4 v4 = *(const ushort4*)&qbuf[(rowbase + q0 + r) * D + hh * 64 + c4 * 4];
    ((float4*)sq)[r * 16 + c4] = make_float4(bf2f(v4.x), bf2f(v4.y), bf2f(v4.z), bf2f(v4.w));
  }

  float mr[4] = {-INFINITY, -INFINITY, -INFINITY, -INFINITY};
  float lr[4] = {0.f, 0.f, 0.f, 0.f};
  float4 acc[4] = {};
  const int ntiles = (q0 + 15) / 64 + 1;

  for (int kt = 0; kt < ntiles; ++kt) {
    __syncthreads();  // protects prior-iter reads and covers the q stage
#pragma unroll
    for (int i = 0; i < 4; ++i) {  // stage k,v: 64 rows x 16 float4 chunks, XOR swizzle
      int cc = t + i * 256;
      int j = cc >> 4, c4 = cc & 15;
      size_t gidx = (rowbase + kt * 64 + j) * D + hh * 64 + c4 * 4;
      ushort4 kk = *(const ushort4*)&kbuf[gidx];
      ushort4 vv = *(const ushort4*)&vbuf[gidx];
      int slot = j * 16 + (c4 ^ (j & 15));
      ((float4*)sk)[slot] = make_float4(bf2f(kk.x), bf2f(kk.y), bf2f(kk.z), bf2f(kk.w));
      ((float4*)sv)[slot] = make_float4(bf2f(vv.x), bf2f(vv.y), bf2f(vv.z), bf2f(vv.w));
    }
    __syncthreads();

    // scores: lane <-> key (kt*64 + lane)
    float s[4] = {0.f, 0.f, 0.f, 0.f};
#pragma unroll 4
    for (int c = 0; c < 16; ++c) {
      float4 k4 = ((const float4*)sk)[lane * 16 + (c ^ (lane & 15))];
#pragma unroll
      for (int r = 0; r < 4; ++r) {
        float4 q4 = ((const float4*)sq)[(wid * 4 + r) * 16 + c];
        s[r] += q4.x * k4.x + q4.y * k4.y + q4.z * k4.z + q4.w * k4.w;
      }
    }
    const int jg = kt * 64 + lane;
    float pp[4];
#pragma unroll
    for (int r = 0; r < 4; ++r) {
      const int qrow = q0 + wid * 4 + r;
      float sval = (jg <= qrow) ? s[r] * 0.125f : -INFINITY;
      float mt = sval;
      for (int off = 1; off < 64; off <<= 1) mt = fmaxf(mt, __shfl_xor(mt, off));
      float mnew = fmaxf(mr[r], mt);
      float scale = __expf(mr[r] - mnew);  // tile 0 always has key 0 -> mnew finite
      float p = __expf(sval - mnew);
      float ls = p;
      for (int off = 1; off < 64; off <<= 1) ls += __shfl_xor(ls, off);
      lr[r] = lr[r] * scale + ls;
      mr[r] = mnew;
      acc[r].x *= scale; acc[r].y *= scale; acc[r].z *= scale; acc[r].w *= scale;
      pp[r] = p;
    }
    // PV: lane = (jj = lane>>4 key group, dd = lane&15 dim group)
    const int dd = lane & 15, jj = lane >> 4;
#pragma unroll 4
    for (int tt = 0; tt < 16; ++tt) {
      int j = jj * 16 + tt;
      float4 v4 = ((const float4*)sv)[j * 16 + (dd ^ (j & 15))];
#pragma unroll
      for (int r = 0; r < 4; ++r) {
        float p = __shfl(pp[r], j);
        acc[r].x += p * v4.x; acc[r].y += p * v4.y;
        acc[r].z += p * v4.z; acc[r].w += p * v4.w;
      }
    }
  }
  // reduce partial acc across the 4 key-groups (lanes xor 16, 32)
#pragma unroll
  for (int r = 0; r < 4; ++r) {
#pragma unroll
    for (int off = 16; off <= 32; off <<= 1) {
      acc[r].x += __shfl_xor(acc[r].x, off);
      acc[r].y += __shfl_xor(acc[r].y, off);
      acc[r].z += __shfl_xor(acc[r].z, off);
      acc[r].w += __shfl_xor(acc[r].w, off);
    }
  }
  if (lane < 16) {
    const int dd = lane;
#pragma unroll
    for (int r = 0; r < 4; ++r) {
      const int qrow = q0 + wid * 4 + r;
      const float inv = 1.0f / lr[r];
      ushort4 o;
      o.x = f2bf(acc[r].x * inv); o.y = f2bf(acc[r].y * inv);
      o.z = f2bf(acc[r].z * inv); o.w = f2bf(acc[r].w * inv);
      *(ushort4*)&ctx[(rowbase + qrow) * D + hh * 64 + dd * 4] = o;
    }
  }
}

// ---------------- host orchestration ----------------
extern "C" void kernel_launch(void* const* d_in, const int* in_sizes, int n_in,
                              void* d_out, int out_size, void* d_ws, size_t ws_size,
                              hipStream_t stream) {
  (void)in_sizes; (void)n_in; (void)out_size;
  const int* x = (const int*)d_in[0];
  const float* tok = (const float*)d_in[1];
  const float* pos = (const float*)d_in[2];
  const float* Wq = (const float*)d_in[3];
  const float* bq = (const float*)d_in[4];
  const float* Wk = (const float*)d_in[5];
  const float* bk = (const float*)d_in[6];
  const float* Wv = (const float*)d_in[7];
  const float* bv = (const float*)d_in[8];
  const float* Wo = (const float*)d_in[9];
  const float* bo = (const float*)d_in[10];
  const float* ln1_g = (const float*)d_in[11];
  const float* ln1_b = (const float*)d_in[12];
  const float* ln2_g = (const float*)d_in[13];
  const float* ln2_b = (const float*)d_in[14];
  const float* W1 = (const float*)d_in[15];
  const float* b1 = (const float*)d_in[16];
  const float* W2 = (const float*)d_in[17];
  const float* b2 = (const float*)d_in[18];
  const float* lnf_g = (const float*)d_in[19];
  const float* lnf_b = (const float*)d_in[20];

  char* ws = (char*)d_ws;
  size_t off = 0;
  auto alloc = [&](size_t bytes) {
    void* p = ws + off;
    off += (bytes + 255) & ~(size_t)255;
    return p;
  };
  u16* wqkvT = (u16*)alloc((size_t)3 * L * D * D * 2);  // [mat][layer][N=768][K=768]
  u16* woT   = (u16*)alloc((size_t)L * D * D * 2);
  u16* w1T   = (u16*)alloc((size_t)L * D * FF * 2);     // [layer][FF][D]
  u16* w2T   = (u16*)alloc((size_t)L * FF * D * 2);     // [layer][D][FF]
  u16* tokT  = (u16*)alloc((size_t)V * D * 2);
  float* h   = (float*)alloc((size_t)M * D * 4);
  u16* x2    = (u16*)alloc((size_t)M * D * 2);
  u16* qkv   = (u16*)alloc((size_t)3 * M * D * 2);
  u16* ctx   = (u16*)alloc((size_t)M * D * 2);
  u16* ffb   = (u16*)alloc((size_t)M * FF * 2);
  u16* hf    = (u16*)alloc((size_t)M * D * 2);
  if (off > ws_size) return;  // insufficient workspace -> loud validation failure

  const dim3 tb(32, 8);
  transpose_cvt<<<dim3(D / 32, D / 32, L), tb, 0, stream>>>(Wq, wqkvT + (size_t)0 * L * D * D, D, D);
  transpose_cvt<<<dim3(D / 32, D / 32, L), tb, 0, stream>>>(Wk, wqkvT + (size_t)1 * L * D * D, D, D);
  transpose_cvt<<<dim3(D / 32, D / 32, L), tb, 0, stream>>>(Wv, wqkvT + (size_t)2 * L * D * D, D, D);
  transpose_cvt<<<dim3(D / 32, D / 32, L), tb, 0, stream>>>(Wo, woT, D, D);
  transpose_cvt<<<dim3(FF / 32, D / 32, L), tb, 0, stream>>>(W1, w1T, D, FF);
  transpose_cvt<<<dim3(D / 32, FF / 32, L), tb, 0, stream>>>(W2, w2T, FF, D);
  convert_bf16<<<2048, 256, 0, stream>>>(tok, tokT, (long)V * D / 4);

  embed_kernel<<<M, 256, 0, stream>>>(x, tok, pos, h);

  for (int l = 0; l < L; ++l) {
    layernorm_kernel<<<M, 256, 0, stream>>>(h, ln1_g + (size_t)l * D, ln1_b + (size_t)l * D, x2);
    // QKV: one launch, z = {q,k,v}
    gemm_nt<0><<<dim3(M / 128, D / 128, 3), 256, 0, stream>>>(
        x2, wqkvT + (size_t)l * D * D, bq + (size_t)l * D, bk + (size_t)l * D, bv + (size_t)l * D,
        nullptr, qkv, nullptr, D, D, (long)L * D * D, (long)M * D);
    attn_kernel<<<dim3(T / 16, Bsz * H), 256, 0, stream>>>(qkv, qkv + (size_t)M * D,
                                                           qkv + (size_t)2 * M * D, ctx);
    // proj + residual into h (f32)
    gemm_nt<2><<<dim3(M / 128, D / 128, 1), 256, 0, stream>>>(
        ctx, woT + (size_t)l * D * D, bo + (size_t)l * D, nullptr, nullptr,
        h, nullptr, h, D, D, 0, 0);
    layernorm_kernel<<<M, 256, 0, stream>>>(h, ln2_g + (size_t)l * D, ln2_b + (size_t)l * D, x2);
    // FF1 + exact GELU -> bf16
    gemm_nt<1><<<dim3(M / 128, FF / 128, 1), 256, 0, stream>>>(
        x2, w1T + (size_t)l * D * FF, b1 + (size_t)l * FF, nullptr, nullptr,
        nullptr, ffb, nullptr, FF, D, 0, 0);
    // FF2 + residual into h
    gemm_nt<2><<<dim3(M / 128, D / 128, 1), 256, 0, stream>>>(
        ffb, w2T + (size_t)l * FF * D, b2 + (size_t)l * D, nullptr, nullptr,
        h, nullptr, h, D, FF, 0, 0);
  }

  layernorm_kernel<<<M, 256, 0, stream>>>(h, lnf_g, lnf_b, hf);
  // LM head: logits = hf @ tokT^T -> f32 d_out
  gemm_nt<3><<<dim3(M / 128, (V + 127) / 128, 1), 256, 0, stream>>>(
      hf, tokT, nullptr, nullptr, nullptr,
      (float*)d_out, nullptr, nullptr, V, D, 0, 0);
}

// Round 2
// 2334.652 us; speedup vs baseline: 2.2325x; 2.2325x over previous
//
#include <hip/hip_runtime.h>
#include <cmath>

#define DI __device__ __forceinline__

typedef unsigned short u16;
typedef __bf16 bf16x8 __attribute__((ext_vector_type(8)));
typedef float f32x4 __attribute__((ext_vector_type(4)));

static constexpr int Bsz = 2, T = 1024, D = 768, H = 12, FF = 3072, V = 50257, L = 12;
static constexpr int M = Bsz * T;  // 2048 rows

DI u16 f2bf(float f) {
  unsigned u = __float_as_uint(f);
  u = (u + 0x7fffu + ((u >> 16) & 1u)) >> 16;
  return (u16)u;
}
DI float bf2f(u16 h) { return __uint_as_float(((unsigned)h) << 16); }

DI void gload_lds16(const void* g, void* l) {
  __builtin_amdgcn_global_load_lds((const __attribute__((address_space(1))) void*)g,
                                   (__attribute__((address_space(3))) void*)l, 16, 0, 0);
}

// ---------------- transpose + convert: src f32 [R][C] -> dst bf16 [C][R] ----------------
__launch_bounds__(256)
__global__ void transpose_cvt(const float* __restrict__ src, u16* __restrict__ dst, int R, int C) {
  __shared__ float tile[32][33];
  const int tx = threadIdx.x, ty = threadIdx.y;
  const int c0 = blockIdx.x * 32, r0 = blockIdx.y * 32;
  src += (size_t)blockIdx.z * R * C;
  dst += (size_t)blockIdx.z * R * C;
#pragma unroll
  for (int i = 0; i < 4; ++i)
    tile[ty + i * 8][tx] = src[(size_t)(r0 + ty + i * 8) * C + c0 + tx];
  __syncthreads();
#pragma unroll
  for (int i = 0; i < 4; ++i)
    dst[(size_t)(c0 + ty + i * 8) * R + r0 + tx] = f2bf(tile[tx][ty + i * 8]);
}

// ---------------- plain convert f32 -> bf16 (tok_emb) ----------------
__global__ void convert_bf16(const float* __restrict__ src, u16* __restrict__ dst, long n4) {
  long i = (long)blockIdx.x * blockDim.x + threadIdx.x;
  long stride = (long)gridDim.x * blockDim.x;
  for (; i < n4; i += stride) {
    float4 f = ((const float4*)src)[i];
    ushort4 o;
    o.x = f2bf(f.x); o.y = f2bf(f.y); o.z = f2bf(f.z); o.w = f2bf(f.w);
    ((ushort4*)dst)[i] = o;
  }
}

// ---------------- embedding: h = tok_emb[x] + pos_emb ----------------
__launch_bounds__(256)
__global__ void embed_kernel(const int* __restrict__ x, const float* __restrict__ tok,
                             const float* __restrict__ pos, float* __restrict__ h) {
  const int row = blockIdx.x, t = threadIdx.x;
  const int tt = row % T;
  const int id = x[row];
  float* o = h + (size_t)row * D;
  const float* te = tok + (size_t)id * D;
  const float* pe = pos + (size_t)tt * D;
  o[t] = te[t] + pe[t];
  o[t + 256] = te[t + 256] + pe[t + 256];
  o[t + 512] = te[t + 512] + pe[t + 512];
}

// ---------------- LayerNorm (biased var), f32 in -> bf16 out ----------------
__launch_bounds__(256)
__global__ void layernorm_kernel(const float* __restrict__ in, const float* __restrict__ gw,
                                 const float* __restrict__ bw, u16* __restrict__ out) {
  const int row = blockIdx.x, t = threadIdx.x;
  const int lane = t & 63, wid = t >> 6;
  const float* x = in + (size_t)row * D;
  float v0 = x[t], v1 = x[t + 256], v2 = x[t + 512];
  float sum = v0 + v1 + v2;
  float sq = v0 * v0 + v1 * v1 + v2 * v2;
  for (int off = 1; off < 64; off <<= 1) {
    sum += __shfl_xor(sum, off);
    sq += __shfl_xor(sq, off);
  }
  __shared__ float ps[4], pq[4];
  if (lane == 0) { ps[wid] = sum; pq[wid] = sq; }
  __syncthreads();
  sum = ps[0] + ps[1] + ps[2] + ps[3];
  sq = pq[0] + pq[1] + pq[2] + pq[3];
  const float mean = sum * (1.0f / D);
  const float var = sq * (1.0f / D) - mean * mean;
  const float rstd = rsqrtf(var + 1e-5f);
  u16* o = out + (size_t)row * D;
  o[t] = f2bf((v0 - mean) * rstd * gw[t] + bw[t]);
  o[t + 256] = f2bf((v1 - mean) * rstd * gw[t + 256] + bw[t + 256]);
  o[t + 512] = f2bf((v2 - mean) * rstd * gw[t + 512] + bw[t + 512]);
}

// ---------------- NT bf16 GEMM core: C[M][N] = A[M][K] * Bt[N][K]^T (+bias) ----------------
// 4 waves in 2x2; wave tile (BM/2)x(BN/2); BK in {32,64}; chunk-XOR LDS swizzle.
// EPI: 0 bf16 (+bias); 1 exact GELU -> bf16 (+bias); 2 f32 resid add; 3 f32 store.
template <int EPI, int BM, int BN, int BK>
DI void gemm_core(const u16* __restrict__ A, const u16* __restrict__ Bt,
                  const float* bias, float* outF, u16* outH, const float* resid,
                  int N, int K) {
  __shared__ u16 sA[BM * BK];
  __shared__ u16 sB[BN * BK];
  constexpr int FM = BM / 32, FN = BN / 32;       // frags per wave (wave = BM/2 x BN/2)
  constexpr int CPR = BK / 8;                     // 16B chunks per row
  constexpr int KS = BK / 32;                     // mfma K-slices per LDS tile
  const int t = threadIdx.x;
  const int lane = t & 63, wid = t >> 6;
  const int m0 = blockIdx.x * BM, n0 = blockIdx.y * BN;

  f32x4 acc[FM][FN] = {};
  const int wr = (wid >> 1) * (BM / 2), wc = (wid & 1) * (BN / 2);
  const int rsel = lane & 15, ksel = lane >> 4;

  for (int k0 = 0; k0 < K; k0 += BK) {
#pragma unroll
    for (int i = 0; i < 2; ++i) {
      int c = t + i * 256;
      int row = c / CPR, ch = c % CPR;
      int g = ch ^ (row & (CPR - 1));
      gload_lds16(A + (size_t)(m0 + row) * K + k0 + g * 8, &sA[c * 8]);
    }
#pragma unroll
    for (int i = 0; i < 2; ++i) {
      int c = t + i * 256;
      int row = c / CPR, ch = c % CPR;
      int g = ch ^ (row & (CPR - 1));
      int nr = n0 + row;
      if (nr >= N) nr = N - 1;  // tail: duplicate row, stores are guarded
      gload_lds16(Bt + (size_t)nr * K + k0 + g * 8, &sB[c * 8]);
    }
    __syncthreads();
#pragma unroll
    for (int ks = 0; ks < KS; ++ks) {
      bf16x8 af[FM], bfr[FN];
#pragma unroll
      for (int m = 0; m < FM; ++m) {
        int row = wr + m * 16 + rsel;
        int ch = (ksel + 4 * ks) ^ (row & (CPR - 1));
        af[m] = *(const bf16x8*)&sA[row * BK + ch * 8];
      }
#pragma unroll
      for (int n = 0; n < FN; ++n) {
        int row = wc + n * 16 + rsel;
        int ch = (ksel + 4 * ks) ^ (row & (CPR - 1));
        bfr[n] = *(const bf16x8*)&sB[row * BK + ch * 8];
      }
#pragma unroll
      for (int m = 0; m < FM; ++m)
#pragma unroll
        for (int n = 0; n < FN; ++n)
          acc[m][n] = __builtin_amdgcn_mfma_f32_16x16x32_bf16(af[m], bfr[n], acc[m][n], 0, 0, 0);
    }
    __syncthreads();
  }

  const int rq = lane >> 4;
#pragma unroll
  for (int m = 0; m < FM; ++m) {
#pragma unroll
    for (int n = 0; n < FN; ++n) {
      const int col = n0 + wc + n * 16 + rsel;
      if (col >= N) continue;
      const float bv = bias ? bias[col] : 0.0f;
#pragma unroll
      for (int i = 0; i < 4; ++i) {
        const int row = m0 + wr + m * 16 + rq * 4 + i;
        float v = acc[m][n][i] + bv;
        const size_t idx = (size_t)row * N + col;
        if (EPI == 0) {
          outH[idx] = f2bf(v);
        } else if (EPI == 1) {
          float ge = 0.5f * v * (1.0f + erff(v * 0.70710678118f));
          outH[idx] = f2bf(ge);
        } else if (EPI == 2) {
          outF[idx] = resid[idx] + v;
        } else {
          outF[idx] = v;
        }
      }
    }
  }
}

// distinct names per role so rocprof disambiguates
__launch_bounds__(256) __global__ void gemm_qkv(const u16* __restrict__ A, const u16* __restrict__ Bt,
                                                const float* b0, const float* b1, const float* b2,
                                                u16* out, long zsB, long zsOut) {
  const int z = blockIdx.z;
  gemm_core<0, 64, 64, 64>(A, Bt + (size_t)z * zsB, z == 0 ? b0 : (z == 1 ? b1 : b2),
                           nullptr, out + (size_t)z * zsOut, nullptr, D, D);
}
__launch_bounds__(256) __global__ void gemm_proj(const u16* __restrict__ A, const u16* __restrict__ Bt,
                                                 const float* bias, float* h) {
  gemm_core<2, 64, 64, 64>(A, Bt, bias, h, nullptr, h, D, D);
}
__launch_bounds__(256) __global__ void gemm_ff1(const u16* __restrict__ A, const u16* __restrict__ Bt,
                                                const float* bias, u16* out) {
  gemm_core<1, 128, 128, 32>(A, Bt, bias, nullptr, out, nullptr, FF, D);
}
__launch_bounds__(256) __global__ void gemm_ff2(const u16* __restrict__ A, const u16* __restrict__ Bt,
                                                const float* bias, float* h) {
  gemm_core<2, 64, 64, 64>(A, Bt, bias, h, nullptr, h, D, FF);
}
__launch_bounds__(256) __global__ void gemm_lm(const u16* __restrict__ A, const u16* __restrict__ Bt,
                                               float* out) {
  gemm_core<3, 128, 128, 32>(A, Bt, nullptr, out, nullptr, nullptr, V, D);
}

// ---------------- MFMA causal flash attention ----------------
// block = 64 q-rows (4 waves x 16), one (b,h); 64-key tiles.
// sK [64][64] chunk-swizzled (gload_lds w/ pre-swizzled source); sVT [d][key] stride 72;
// per-wave sP [q][key] stride 72 for the C-layout -> A-layout bounce.
__launch_bounds__(256)
__global__ void attn_mfma(const u16* __restrict__ qbuf, const u16* __restrict__ kbuf,
                          const u16* __restrict__ vbuf, u16* __restrict__ ctx) {
  __shared__ u16 sK[64 * 64];
  __shared__ u16 sVT[64 * 72];
  __shared__ u16 sP[4][16 * 72];
  const int t = threadIdx.x, lane = t & 63, wid = t >> 6;
  const int l15 = lane & 15, g = lane >> 4;
  const int q0 = blockIdx.x * 64;
  const int bh = blockIdx.y;
  const int b = bh / H, hh = bh % H;
  const size_t rowbase = (size_t)b * T;
  u16* sPw = &sP[wid][0];

  // Q fragments in registers: rows q0+wid*16+l15, dims hh*64 + g*8 + kb*32
  const size_t qoff = (rowbase + q0 + wid * 16 + l15) * D + hh * 64 + g * 8;
  bf16x8 aQ0 = *(const bf16x8*)&qbuf[qoff];
  bf16x8 aQ1 = *(const bf16x8*)&qbuf[qoff + 32];

  float mr[4] = {-INFINITY, -INFINITY, -INFINITY, -INFINITY};
  float lr[4] = {0.f, 0.f, 0.f, 0.f};
  f32x4 o[4] = {};
  const int nt = blockIdx.x + 1;

  for (int kt = 0; kt < nt; ++kt) {
    __syncthreads();  // prior-tile reads done before overwrite
    // stage K: linear LDS dest, pre-swizzled global source chunk (rule 21)
#pragma unroll
    for (int i = 0; i < 2; ++i) {
      int c = t + i * 256;               // 0..511
      int row = c >> 3, ch = c & 7;
      gload_lds16(kbuf + (rowbase + kt * 64 + row) * D + hh * 64 + (size_t)(ch ^ (row & 7)) * 8,
                  &sK[c * 8]);
    }
    // stage V transposed: [d][key] stride 72
#pragma unroll
    for (int i = 0; i < 2; ++i) {
      int key = t & 63, d0 = (t >> 6) * 8 + i * 32;
      bf16x8 v8 = *(const bf16x8*)&vbuf[(rowbase + kt * 64 + key) * D + hh * 64 + d0];
#pragma unroll
      for (int j = 0; j < 8; ++j) sVT[(d0 + j) * 72 + key] = ((u16*)&v8)[j];
    }
    __syncthreads();

    // QK^T: S[16q][64k] = 4 key-frags x 2 mfma
    f32x4 s[4];
#pragma unroll
    for (int f = 0; f < 4; ++f) {
      const int krow = f * 16 + l15;
      bf16x8 bk0 = *(const bf16x8*)&sK[krow * 64 + ((g ^ (krow & 7)) * 8)];
      bf16x8 bk1 = *(const bf16x8*)&sK[krow * 64 + (((g + 4) ^ (krow & 7)) * 8)];
      f32x4 z = {};
      z = __builtin_amdgcn_mfma_f32_16x16x32_bf16(aQ0, bk0, z, 0, 0, 0);
      s[f] = __builtin_amdgcn_mfma_f32_16x16x32_bf16(aQ1, bk1, z, 0, 0, 0);
    }

    // online softmax per q-row (rows live in (g,i); keys in (f,l15))
    float p[4][4], scl[4];
#pragma unroll
    for (int i = 0; i < 4; ++i) {
      const int qrow = q0 + wid * 16 + g * 4 + i;
      const int kb = kt * 64 + l15;
      float v0 = (kb <= qrow) ? s[0][i] * 0.125f : -INFINITY;
      float v1 = (kb + 16 <= qrow) ? s[1][i] * 0.125f : -INFINITY;
      float v2 = (kb + 32 <= qrow) ? s[2][i] * 0.125f : -INFINITY;
      float v3 = (kb + 48 <= qrow) ? s[3][i] * 0.125f : -INFINITY;
      float mt = fmaxf(fmaxf(v0, v1), fmaxf(v2, v3));
#pragma unroll
      for (int off = 1; off < 16; off <<= 1) mt = fmaxf(mt, __shfl_xor(mt, off));
      const float mn = fmaxf(mr[i], mt);
      const float sc = __expf(mr[i] - mn);
      p[0][i] = __expf(v0 - mn); p[1][i] = __expf(v1 - mn);
      p[2][i] = __expf(v2 - mn); p[3][i] = __expf(v3 - mn);
      float rs = p[0][i] + p[1][i] + p[2][i] + p[3][i];
#pragma unroll
      for (int off = 1; off < 16; off <<= 1) rs += __shfl_xor(rs, off);
      lr[i] = lr[i] * sc + rs;
      mr[i] = mn;
      scl[i] = sc;
    }
#pragma unroll
    for (int n = 0; n < 4; ++n) {
      o[n][0] *= scl[0]; o[n][1] *= scl[1]; o[n][2] *= scl[2]; o[n][3] *= scl[3];
    }
    // P -> per-wave LDS (C-layout scatter, A-layout gather)
#pragma unroll
    for (int f = 0; f < 4; ++f)
#pragma unroll
      for (int i = 0; i < 4; ++i)
        sPw[(g * 4 + i) * 72 + f * 16 + l15] = f2bf(p[f][i]);

    // PV: O[16q][64d] += P[16q][64k] V[64k][64d]
#pragma unroll
    for (int kb = 0; kb < 2; ++kb) {
      bf16x8 pa = *(const bf16x8*)&sPw[l15 * 72 + kb * 32 + g * 8];
#pragma unroll
      for (int n = 0; n < 4; ++n) {
        bf16x8 bv = *(const bf16x8*)&sVT[(n * 16 + l15) * 72 + kb * 32 + g * 8];
        o[n] = __builtin_amdgcn_mfma_f32_16x16x32_bf16(pa, bv, o[n], 0, 0, 0);
      }
    }
  }

  float inv[4] = {1.0f / lr[0], 1.0f / lr[1], 1.0f / lr[2], 1.0f / lr[3]};
#pragma unroll
  for (int n = 0; n < 4; ++n)
#pragma unroll
    for (int i = 0; i < 4; ++i)
      ctx[(rowbase + q0 + wid * 16 + g * 4 + i) * D + hh * 64 + n * 16 + l15] =
          f2bf(o[n][i] * inv[i]);
}

// ---------------- host orchestration ----------------
extern "C" void kernel_launch(void* const* d_in, const int* in_sizes, int n_in,
                              void* d_out, int out_size, void* d_ws, size_t ws_size,
                              hipStream_t stream) {
  (void)in_sizes; (void)n_in; (void)out_size;
  const int* x = (const int*)d_in[0];
  const float* tok = (const float*)d_in[1];
  const float* pos = (const float*)d_in[2];
  const float* Wq = (const float*)d_in[3];
  const float* bq = (const float*)d_in[4];
  const float* Wk = (const float*)d_in[5];
  const float* bk = (const float*)d_in[6];
  const float* Wv = (const float*)d_in[7];
  const float* bv = (const float*)d_in[8];
  const float* Wo = (const float*)d_in[9];
  const float* bo = (const float*)d_in[10];
  const float* ln1_g = (const float*)d_in[11];
  const float* ln1_b = (const float*)d_in[12];
  const float* ln2_g = (const float*)d_in[13];
  const float* ln2_b = (const float*)d_in[14];
  const float* W1 = (const float*)d_in[15];
  const float* b1 = (const float*)d_in[16];
  const float* W2 = (const float*)d_in[17];
  const float* b2 = (const float*)d_in[18];
  const float* lnf_g = (const float*)d_in[19];
  const float* lnf_b = (const float*)d_in[20];

  char* ws = (char*)d_ws;
  size_t off = 0;
  auto alloc = [&](size_t bytes) {
    void* p = ws + off;
    off += (bytes + 255) & ~(size_t)255;
    return p;
  };
  u16* wqkvT = (u16*)alloc((size_t)3 * L * D * D * 2);  // [mat][layer][N][K]
  u16* woT   = (u16*)alloc((size_t)L * D * D * 2);
  u16* w1T   = (u16*)alloc((size_t)L * D * FF * 2);     // [layer][FF][D]
  u16* w2T   = (u16*)alloc((size_t)L * FF * D * 2);     // [layer][D][FF]
  u16* tokT  = (u16*)alloc((size_t)V * D * 2);
  float* h   = (float*)alloc((size_t)M * D * 4);
  u16* x2    = (u16*)alloc((size_t)M * D * 2);
  u16* qkv   = (u16*)alloc((size_t)3 * M * D * 2);
  u16* ctx   = (u16*)alloc((size_t)M * D * 2);
  u16* ffb   = (u16*)alloc((size_t)M * FF * 2);
  u16* hf    = (u16*)alloc((size_t)M * D * 2);
  if (off > ws_size) return;  // insufficient workspace -> loud validation failure

  const dim3 tb(32, 8);
  transpose_cvt<<<dim3(D / 32, D / 32, L), tb, 0, stream>>>(Wq, wqkvT + (size_t)0 * L * D * D, D, D);
  transpose_cvt<<<dim3(D / 32, D / 32, L), tb, 0, stream>>>(Wk, wqkvT + (size_t)1 * L * D * D, D, D);
  transpose_cvt<<<dim3(D / 32, D / 32, L), tb, 0, stream>>>(Wv, wqkvT + (size_t)2 * L * D * D, D, D);
  transpose_cvt<<<dim3(D / 32, D / 32, L), tb, 0, stream>>>(Wo, woT, D, D);
  transpose_cvt<<<dim3(FF / 32, D / 32, L), tb, 0, stream>>>(W1, w1T, D, FF);
  transpose_cvt<<<dim3(D / 32, FF / 32, L), tb, 0, stream>>>(W2, w2T, FF, D);
  convert_bf16<<<2048, 256, 0, stream>>>(tok, tokT, (long)V * D / 4);

  embed_kernel<<<M, 256, 0, stream>>>(x, tok, pos, h);

  for (int l = 0; l < L; ++l) {
    layernorm_kernel<<<M, 256, 0, stream>>>(h, ln1_g + (size_t)l * D, ln1_b + (size_t)l * D, x2);
    gemm_qkv<<<dim3(M / 64, D / 64, 3), 256, 0, stream>>>(
        x2, wqkvT + (size_t)l * D * D, bq + (size_t)l * D, bk + (size_t)l * D, bv + (size_t)l * D,
        qkv, (long)L * D * D, (long)M * D);
    attn_mfma<<<dim3(T / 64, Bsz * H), 256, 0, stream>>>(qkv, qkv + (size_t)M * D,
                                                         qkv + (size_t)2 * M * D, ctx);
    gemm_proj<<<dim3(M / 64, D / 64), 256, 0, stream>>>(ctx, woT + (size_t)l * D * D,
                                                        bo + (size_t)l * D, h);
    layernorm_kernel<<<M, 256, 0, stream>>>(h, ln2_g + (size_t)l * D, ln2_b + (size_t)l * D, x2);
    gemm_ff1<<<dim3(M / 128, FF / 128), 256, 0, stream>>>(x2, w1T + (size_t)l * D * FF,
                                                          b1 + (size_t)l * FF, ffb);
    gemm_ff2<<<dim3(M / 64, D / 64), 256, 0, stream>>>(ffb, w2T + (size_t)l * FF * D,
                                                       b2 + (size_t)l * D, h);
  }

  layernorm_kernel<<<M, 256, 0, stream>>>(h, lnf_g, lnf_b, hf);
  gemm_lm<<<dim3(M / 128, (V + 127) / 128), 256, 0, stream>>>(hf, tokT, (float*)d_out);
}